// Round 1
// baseline (513.211 us; speedup 1.0000x reference)
//
#include <hip/hip_runtime.h>
#include <math.h>

namespace {

constexpr int NN  = 50000;   // nodes
constexpr int NE  = 800000;  // edges
constexpr int FIN = 128;     // in features
constexpr int CH  = 96;      // conv hidden
constexpr int LH  = 64;      // lin hidden
constexpr int NC  = 10;      // classes
constexpr int NG  = 128;     // graphs
constexpr int NB_NODES = (NN + 255) / 256;  // 196 blocks over nodes

// ---------------- graph-structure build (once per call) ----------------

__global__ void k_init(float* __restrict__ deg, int* __restrict__ cnt) {
  int i = blockIdx.x * 256 + threadIdx.x;
  if (i < NN) { deg[i] = 1.0f; cnt[i] = 0; }  // self-loop weight 1
}

__global__ void k_count(const int* __restrict__ ei, const float* __restrict__ ew,
                        float* __restrict__ deg, int* __restrict__ cnt) {
  int e = blockIdx.x * 256 + threadIdx.x;
  if (e < NE) {
    int c = ei[NE + e];            // col
    atomicAdd(&deg[c], ew[e]);
    atomicAdd(&cnt[c], 1);
  }
}

__global__ void k_dinv(float* __restrict__ deg) {
  int i = blockIdx.x * 256 + threadIdx.x;
  if (i < NN) {
    float d = deg[i];
    deg[i] = d > 0.f ? 1.0f / sqrtf(d) : 0.f;   // in-place: deg -> dinv
  }
}

__global__ void k_scan1(const int* __restrict__ cnt, int* __restrict__ incl,
                        int* __restrict__ bsum) {
  __shared__ int s[256];
  int t = threadIdx.x, i = blockIdx.x * 256 + t;
  s[t] = (i < NN) ? cnt[i] : 0;
  for (int off = 1; off < 256; off <<= 1) {
    __syncthreads();
    int u = (t >= off) ? s[t - off] : 0;
    __syncthreads();
    s[t] += u;
  }
  if (i < NN) incl[i] = s[t];
  if (t == 255) bsum[blockIdx.x] = s[255];
}

__global__ void k_scan2(int* __restrict__ bsum) {
  __shared__ int s[256];
  int t = threadIdx.x;
  int v = (t < NB_NODES) ? bsum[t] : 0;
  s[t] = v;
  for (int off = 1; off < 256; off <<= 1) {
    __syncthreads();
    int u = (t >= off) ? s[t - off] : 0;
    __syncthreads();
    s[t] += u;
  }
  if (t < NB_NODES) bsum[t] = s[t] - v;  // exclusive block offsets
}

__global__ void k_scan3(const int* __restrict__ cnt, int* __restrict__ offs,
                        const int* __restrict__ bsum, int* __restrict__ cursor) {
  int t = threadIdx.x, i = blockIdx.x * 256 + t;
  if (i < NN) {
    int e = offs[i] - cnt[i] + bsum[blockIdx.x];  // inclusive -> exclusive + block base
    offs[i] = e;
    cursor[i] = e;
  }
}

__global__ void k_fill(const int* __restrict__ ei, const float* __restrict__ ew,
                       const float* __restrict__ dinv, int* __restrict__ cursor,
                       int2* __restrict__ epack) {
  int e = blockIdx.x * 256 + threadIdx.x;
  if (e < NE) {
    int r = ei[e], c = ei[NE + e];
    int slot = atomicAdd(&cursor[c], 1);
    float cf = dinv[r] * ew[e] * dinv[c];
    epack[slot] = make_int2(r, __float_as_int(cf));
  }
}

// ---------------- GEMM: Y[NN][CH] = X[NN][K] @ W[K][CH] ----------------
// 24-node tile, 192 threads: thread = (node nl = tid>>3, colgroup cg = tid&7) -> 12 cols.
// W fully in LDS; X tile in LDS with +4 pad (conflict-free b128 reads).

template <int K>
__global__ __launch_bounds__(192) void k_gemm(const float* __restrict__ X,
                                              const float* __restrict__ Wg,
                                              float* __restrict__ Y) {
  constexpr int PAD = 4;
  __shared__ float sW[K * CH];
  __shared__ float sX[24 * (K + PAD)];
  int tid = threadIdx.x;
  int n0 = blockIdx.x * 24;
  for (int i = tid; i < K * CH; i += 192) sW[i] = Wg[i];
  for (int i = tid; i < 24 * K; i += 192) {
    int nl = i / K, k = i - nl * K;
    int n = n0 + nl;
    sX[nl * (K + PAD) + k] = (n < NN) ? X[n * K + k] : 0.f;
  }
  __syncthreads();
  int nl = tid >> 3, cg = tid & 7;
  float acc[12];
#pragma unroll
  for (int j = 0; j < 12; ++j) acc[j] = 0.f;
  const float* xrow = &sX[nl * (K + PAD)];
#pragma unroll 8
  for (int k4 = 0; k4 < K / 4; ++k4) {
    float4 xq = *(const float4*)&xrow[k4 * 4];
#pragma unroll
    for (int i = 0; i < 4; ++i) {
      float xv = (i == 0) ? xq.x : (i == 1) ? xq.y : (i == 2) ? xq.z : xq.w;
      const float4* wv = (const float4*)&sW[(k4 * 4 + i) * CH + cg * 12];
      float4 w0 = wv[0], w1 = wv[1], w2 = wv[2];
      acc[0] += xv * w0.x; acc[1] += xv * w0.y; acc[2] += xv * w0.z; acc[3] += xv * w0.w;
      acc[4] += xv * w1.x; acc[5] += xv * w1.y; acc[6] += xv * w1.z; acc[7] += xv * w1.w;
      acc[8] += xv * w2.x; acc[9] += xv * w2.y; acc[10] += xv * w2.z; acc[11] += xv * w2.w;
    }
  }
  int n = n0 + nl;
  if (n < NN) {
    float4* o = (float4*)&Y[n * CH + cg * 12];
    o[0] = make_float4(acc[0], acc[1], acc[2], acc[3]);
    o[1] = make_float4(acc[4], acc[5], acc[6], acc[7]);
    o[2] = make_float4(acc[8], acc[9], acc[10], acc[11]);
  }
}

// ---------------- aggregation: H[n] = dinv[n]^2*Y[n] + sum_e coef*Y[src] + b --------
// 8 nodes/block, 32 lanes/node (24 active), float4 feature chunks.

template <bool RELU>
__global__ __launch_bounds__(256) void k_agg(const float* __restrict__ Y,
                                             const int* __restrict__ offs,
                                             const int* __restrict__ cnt,
                                             const int2* __restrict__ epack,
                                             const float* __restrict__ dinv,
                                             const float* __restrict__ bias,
                                             float* __restrict__ H) {
  int tid = threadIdx.x;
  int nl = tid >> 5;
  int fq = tid & 31;
  int n = blockIdx.x * 8 + nl;
  if (n >= NN || fq >= CH / 4) return;
  const float4* Y4 = (const float4*)Y;
  float d = dinv[n];
  float sc = d * d;
  float4 sv = Y4[n * (CH / 4) + fq];
  float ax = sc * sv.x, ay = sc * sv.y, az = sc * sv.z, aw = sc * sv.w;
  int s = offs[n], e = s + cnt[n];
  for (int j = s; j < e; ++j) {
    int2 ep = epack[j];
    float cf = __int_as_float(ep.y);
    float4 yv = Y4[ep.x * (CH / 4) + fq];
    ax += cf * yv.x; ay += cf * yv.y; az += cf * yv.z; aw += cf * yv.w;
  }
  float4 bv = ((const float4*)bias)[fq];
  ax += bv.x; ay += bv.y; az += bv.z; aw += bv.w;
  if (RELU) {
    ax = fmaxf(ax, 0.f); ay = fmaxf(ay, 0.f);
    az = fmaxf(az, 0.f); aw = fmaxf(aw, 0.f);
  }
  ((float4*)H)[n * (CH / 4) + fq] = make_float4(ax, ay, az, aw);
}

// ---------------- pool + MLP ----------------

__global__ void k_gstart(const int* __restrict__ batch, int* __restrict__ gstart) {
  int i = blockIdx.x * 256 + threadIdx.x;
  if (i < NN) {
    int g = batch[i];
    if (i == 0 || batch[i - 1] != g) gstart[g] = i;
    if (i == NN - 1) gstart[NG] = NN;
  }
}

__global__ void k_pool(const float* __restrict__ H, const int* __restrict__ gstart,
                       float* __restrict__ part) {
  int g = blockIdx.x, q = blockIdx.y, f = threadIdx.x;
  if (f >= CH) return;
  int s = gstart[g], e = gstart[g + 1];
  int len = e - s;
  int a = s + (int)(((long long)len * q) / 4);
  int b = s + (int)(((long long)len * (q + 1)) / 4);
  float m = -INFINITY;
  for (int n = a; n < b; ++n) m = fmaxf(m, H[n * CH + f]);
  part[(g * 4 + q) * CH + f] = m;
}

__global__ void k_mlp(const float* __restrict__ part, const float* __restrict__ Wl1,
                      const float* __restrict__ bl1, const float* __restrict__ Wl2,
                      const float* __restrict__ bl2, float* __restrict__ out) {
  __shared__ float p[CH];
  __shared__ float hs[LH];
  int g = blockIdx.x, t = threadIdx.x;
  if (t < CH) {
    float m = part[(g * 4 + 0) * CH + t];
    m = fmaxf(m, part[(g * 4 + 1) * CH + t]);
    m = fmaxf(m, part[(g * 4 + 2) * CH + t]);
    m = fmaxf(m, part[(g * 4 + 3) * CH + t]);
    p[t] = fmaxf(m, 0.f);  // relu(max) == max(relu)
  }
  __syncthreads();
  if (t < LH) {
    float a = bl1[t];
#pragma unroll 4
    for (int k = 0; k < CH; ++k) a += p[k] * Wl1[k * LH + t];
    hs[t] = fmaxf(a, 0.f);
  }
  __syncthreads();
  if (t < NC) {
    float a = bl2[t];
#pragma unroll 4
    for (int k = 0; k < LH; ++k) a += hs[k] * Wl2[k * NC + t];
    out[g * NC + t] = a;
  }
}

}  // namespace

extern "C" void kernel_launch(void* const* d_in, const int* in_sizes, int n_in,
                              void* d_out, int out_size, void* d_ws, size_t ws_size,
                              hipStream_t stream) {
  const float* x   = (const float*)d_in[0];
  const int*   ei  = (const int*)d_in[1];
  const float* ew  = (const float*)d_in[2];
  const int*   bat = (const int*)d_in[3];
  const float* W1  = (const float*)d_in[4];
  const float* b1  = (const float*)d_in[5];
  const float* W2  = (const float*)d_in[6];
  const float* b2  = (const float*)d_in[7];
  const float* W3  = (const float*)d_in[8];
  const float* b3  = (const float*)d_in[9];
  const float* Wl1 = (const float*)d_in[10];
  const float* bl1 = (const float*)d_in[11];
  const float* Wl2 = (const float*)d_in[12];
  const float* bl2 = (const float*)d_in[13];
  float* out = (float*)d_out;

  // workspace carve-up (256B aligned)
  char* base = (char*)d_ws;
  size_t o = 0;
  auto carve = [&](size_t bytes) {
    char* p = base + o;
    o = (o + bytes + 255) & ~(size_t)255;
    return p;
  };
  float* dinv   = (float*)carve(NN * 4);       // deg -> dinv in place
  int*   cnt    = (int*)carve(NN * 4);
  int*   offs   = (int*)carve(NN * 4);
  int*   cursor = (int*)carve(NN * 4);
  int*   bsum   = (int*)carve(256 * 4);
  int*   gstart = (int*)carve((NG + 1) * 4);
  float* part   = (float*)carve(NG * 4 * CH * 4);
  int2*  epack  = (int2*)carve((size_t)NE * 8);
  float* Y      = (float*)carve((size_t)NN * CH * 4);
  float* H      = (float*)carve((size_t)NN * CH * 4);
  (void)ws_size; (void)n_in; (void)in_sizes; (void)out_size;

  const int GB_N = NB_NODES;                 // 196
  const int GB_E = (NE + 255) / 256;         // 3125
  const int GB_G = (NN + 23) / 24;           // gemm blocks
  const int GB_A = (NN + 7) / 8;             // agg blocks

  // graph structure (shared by all 3 conv layers)
  k_init<<<GB_N, 256, 0, stream>>>(dinv, cnt);
  k_count<<<GB_E, 256, 0, stream>>>(ei, ew, dinv, cnt);
  k_dinv<<<GB_N, 256, 0, stream>>>(dinv);
  k_scan1<<<GB_N, 256, 0, stream>>>(cnt, offs, bsum);
  k_scan2<<<1, 256, 0, stream>>>(bsum);
  k_scan3<<<GB_N, 256, 0, stream>>>(cnt, offs, bsum, cursor);
  k_fill<<<GB_E, 256, 0, stream>>>(ei, ew, dinv, cursor, epack);

  // layer 1
  k_gemm<FIN><<<GB_G, 192, 0, stream>>>(x, W1, Y);
  k_agg<true><<<GB_A, 256, 0, stream>>>(Y, offs, cnt, epack, dinv, b1, H);
  // layer 2
  k_gemm<CH><<<GB_G, 192, 0, stream>>>(H, W2, Y);
  k_agg<true><<<GB_A, 256, 0, stream>>>(Y, offs, cnt, epack, dinv, b2, H);
  // layer 3
  k_gemm<CH><<<GB_G, 192, 0, stream>>>(H, W3, Y);
  k_agg<false><<<GB_A, 256, 0, stream>>>(Y, offs, cnt, epack, dinv, b3, H);

  // pool + MLP
  k_gstart<<<GB_N, 256, 0, stream>>>(bat, gstart);
  k_pool<<<dim3(NG, 4), 128, 0, stream>>>(H, gstart, part);
  k_mlp<<<NG, 128, 0, stream>>>(part, Wl1, bl1, Wl2, bl2, out);
}

// Round 2
// 427.868 us; speedup vs baseline: 1.1995x; 1.1995x over previous
//
#include <hip/hip_runtime.h>
#include <math.h>

namespace {

constexpr int NN  = 50000;   // nodes
constexpr int NE  = 800000;  // edges
constexpr int FIN = 128;     // in features
constexpr int CH  = 96;      // conv hidden
constexpr int LH  = 64;      // lin hidden
constexpr int NC  = 10;      // classes
constexpr int NG  = 128;     // graphs
constexpr int NB_NODES = (NN + 255) / 256;  // 196 blocks over nodes

// ---------------- graph-structure build (once per call) ----------------

__global__ void k_init(float* __restrict__ deg, int* __restrict__ cnt) {
  int i = blockIdx.x * 256 + threadIdx.x;
  if (i < NN) { deg[i] = 1.0f; cnt[i] = 0; }  // self-loop weight 1
}

__global__ void k_count(const int* __restrict__ ei, const float* __restrict__ ew,
                        float* __restrict__ deg, int* __restrict__ cnt) {
  int e = blockIdx.x * 256 + threadIdx.x;
  if (e < NE) {
    int c = ei[NE + e];            // col
    atomicAdd(&deg[c], ew[e]);
    atomicAdd(&cnt[c], 1);
  }
}

__global__ void k_dinv(float* __restrict__ deg) {
  int i = blockIdx.x * 256 + threadIdx.x;
  if (i < NN) {
    float d = deg[i];
    deg[i] = d > 0.f ? 1.0f / sqrtf(d) : 0.f;   // in-place: deg -> dinv
  }
}

__global__ void k_scan1(const int* __restrict__ cnt, int* __restrict__ incl,
                        int* __restrict__ bsum) {
  __shared__ int s[256];
  int t = threadIdx.x, i = blockIdx.x * 256 + t;
  s[t] = (i < NN) ? cnt[i] : 0;
  for (int off = 1; off < 256; off <<= 1) {
    __syncthreads();
    int u = (t >= off) ? s[t - off] : 0;
    __syncthreads();
    s[t] += u;
  }
  if (i < NN) incl[i] = s[t];
  if (t == 255) bsum[blockIdx.x] = s[255];
}

__global__ void k_scan2(int* __restrict__ bsum) {
  __shared__ int s[256];
  int t = threadIdx.x;
  int v = (t < NB_NODES) ? bsum[t] : 0;
  s[t] = v;
  for (int off = 1; off < 256; off <<= 1) {
    __syncthreads();
    int u = (t >= off) ? s[t - off] : 0;
    __syncthreads();
    s[t] += u;
  }
  if (t < NB_NODES) bsum[t] = s[t] - v;  // exclusive block offsets
}

__global__ void k_scan3(const int* __restrict__ cnt, int* __restrict__ offs,
                        const int* __restrict__ bsum, int* __restrict__ cursor) {
  int t = threadIdx.x, i = blockIdx.x * 256 + t;
  if (i < NN) {
    int e = offs[i] - cnt[i] + bsum[blockIdx.x];  // inclusive -> exclusive + block base
    offs[i] = e;
    cursor[i] = e;
  }
}

__global__ void k_fill(const int* __restrict__ ei, const float* __restrict__ ew,
                       const float* __restrict__ dinv, int* __restrict__ cursor,
                       int2* __restrict__ epack) {
  int e = blockIdx.x * 256 + threadIdx.x;
  if (e < NE) {
    int r = ei[e], c = ei[NE + e];
    int slot = atomicAdd(&cursor[c], 1);
    float cf = dinv[r] * ew[e] * dinv[c];
    epack[slot] = make_int2(r, __float_as_int(cf));
  }
}

// ---------------- GEMM: Y[NN][CH] = X[NN][K] @ W[K][CH] ----------------
// 64-node tile, 128 threads; thread = (a = tid>>3 in [0,16), cg = tid&7).
// Register micro-tile: 4 nodes (a, a+16, a+32, a+48) x 12 cols (cg*12..).
// K chunked at KC=32: sW[32][96] = 12.3KB, sX[64][33] = 8.4KB -> 20.7KB LDS.

template <int K>
__global__ __launch_bounds__(128) void k_gemm(const float* __restrict__ X,
                                              const float* __restrict__ Wg,
                                              float* __restrict__ Y) {
  constexpr int KC  = 32;
  constexpr int LDX = KC + 1;  // 33: stride-33 rows -> conflict-free x reads
  __shared__ float sX[64 * LDX];
  __shared__ float sW[KC * CH];
  int tid = threadIdx.x;
  int n0 = blockIdx.x * 64;
  int a = tid >> 3, cg = tid & 7;
  float acc[4][12];
#pragma unroll
  for (int j = 0; j < 4; ++j)
#pragma unroll
    for (int i = 0; i < 12; ++i) acc[j][i] = 0.f;

  for (int kc = 0; kc < K; kc += KC) {
    __syncthreads();  // protect previous chunk's LDS reads
    // stage W chunk: KC*CH/4 = 768 float4-words? no: KC*CH = 3072 floats = 768 float4
    {
      const float4* src = (const float4*)(Wg + (size_t)kc * CH);
      float4* dst = (float4*)sW;
#pragma unroll
      for (int i = 0; i < 6; ++i) dst[tid + i * 128] = src[tid + i * 128];
    }
    // stage X chunk: 64 rows x 8 float4 each
    {
#pragma unroll
      for (int p = 0; p < 4; ++p) {
        int i = tid + p * 128;
        int r = i >> 3, c = i & 7;
        int n = n0 + r;
        float4 v = (n < NN) ? *(const float4*)(X + (size_t)n * K + kc + c * 4)
                            : make_float4(0.f, 0.f, 0.f, 0.f);
        float* d = &sX[r * LDX + c * 4];
        d[0] = v.x; d[1] = v.y; d[2] = v.z; d[3] = v.w;
      }
    }
    __syncthreads();
#pragma unroll 8
    for (int k = 0; k < KC; ++k) {
      float xv[4];
#pragma unroll
      for (int j = 0; j < 4; ++j) xv[j] = sX[(a + j * 16) * LDX + k];
      const float4* wr = (const float4*)&sW[k * CH + cg * 12];
      float4 w0 = wr[0], w1 = wr[1], w2 = wr[2];
#pragma unroll
      for (int j = 0; j < 4; ++j) {
        acc[j][0] += xv[j] * w0.x; acc[j][1]  += xv[j] * w0.y;
        acc[j][2] += xv[j] * w0.z; acc[j][3]  += xv[j] * w0.w;
        acc[j][4] += xv[j] * w1.x; acc[j][5]  += xv[j] * w1.y;
        acc[j][6] += xv[j] * w1.z; acc[j][7]  += xv[j] * w1.w;
        acc[j][8] += xv[j] * w2.x; acc[j][9]  += xv[j] * w2.y;
        acc[j][10] += xv[j] * w2.z; acc[j][11] += xv[j] * w2.w;
      }
    }
  }
#pragma unroll
  for (int j = 0; j < 4; ++j) {
    int n = n0 + a + j * 16;
    if (n < NN) {
      float4* o = (float4*)&Y[(size_t)n * CH + cg * 12];
      o[0] = make_float4(acc[j][0], acc[j][1], acc[j][2], acc[j][3]);
      o[1] = make_float4(acc[j][4], acc[j][5], acc[j][6], acc[j][7]);
      o[2] = make_float4(acc[j][8], acc[j][9], acc[j][10], acc[j][11]);
    }
  }
}

// ---------------- aggregation: H[n] = dinv[n]^2*Y[n] + sum_e coef*Y[src] + b --------
// 8 nodes/block, 32 lanes/node (24 active), float4 feature chunks.

template <bool RELU>
__global__ __launch_bounds__(256) void k_agg(const float* __restrict__ Y,
                                             const int* __restrict__ offs,
                                             const int* __restrict__ cnt,
                                             const int2* __restrict__ epack,
                                             const float* __restrict__ dinv,
                                             const float* __restrict__ bias,
                                             float* __restrict__ H) {
  int tid = threadIdx.x;
  int nl = tid >> 5;
  int fq = tid & 31;
  int n = blockIdx.x * 8 + nl;
  if (n >= NN || fq >= CH / 4) return;
  const float4* Y4 = (const float4*)Y;
  float d = dinv[n];
  float sc = d * d;
  float4 sv = Y4[n * (CH / 4) + fq];
  float ax = sc * sv.x, ay = sc * sv.y, az = sc * sv.z, aw = sc * sv.w;
  int s = offs[n], e = s + cnt[n];
  for (int j = s; j < e; ++j) {
    int2 ep = epack[j];
    float cf = __int_as_float(ep.y);
    float4 yv = Y4[ep.x * (CH / 4) + fq];
    ax += cf * yv.x; ay += cf * yv.y; az += cf * yv.z; aw += cf * yv.w;
  }
  float4 bv = ((const float4*)bias)[fq];
  ax += bv.x; ay += bv.y; az += bv.z; aw += bv.w;
  if (RELU) {
    ax = fmaxf(ax, 0.f); ay = fmaxf(ay, 0.f);
    az = fmaxf(az, 0.f); aw = fmaxf(aw, 0.f);
  }
  ((float4*)H)[n * (CH / 4) + fq] = make_float4(ax, ay, az, aw);
}

// ---------------- pool + MLP ----------------

__global__ void k_gstart(const int* __restrict__ batch, int* __restrict__ gstart) {
  int i = blockIdx.x * 256 + threadIdx.x;
  if (i < NN) {
    int g = batch[i];
    if (i == 0 || batch[i - 1] != g) gstart[g] = i;
    if (i == NN - 1) gstart[NG] = NN;
  }
}

__global__ void k_pool(const float* __restrict__ H, const int* __restrict__ gstart,
                       float* __restrict__ part) {
  int g = blockIdx.x, q = blockIdx.y, f = threadIdx.x;
  if (f >= CH) return;
  int s = gstart[g], e = gstart[g + 1];
  int len = e - s;
  int a = s + (int)(((long long)len * q) / 4);
  int b = s + (int)(((long long)len * (q + 1)) / 4);
  float m = -INFINITY;
  for (int n = a; n < b; ++n) m = fmaxf(m, H[n * CH + f]);
  part[(g * 4 + q) * CH + f] = m;
}

__global__ void k_mlp(const float* __restrict__ part, const float* __restrict__ Wl1,
                      const float* __restrict__ bl1, const float* __restrict__ Wl2,
                      const float* __restrict__ bl2, float* __restrict__ out) {
  __shared__ float p[CH];
  __shared__ float hs[LH];
  int g = blockIdx.x, t = threadIdx.x;
  if (t < CH) {
    float m = part[(g * 4 + 0) * CH + t];
    m = fmaxf(m, part[(g * 4 + 1) * CH + t]);
    m = fmaxf(m, part[(g * 4 + 2) * CH + t]);
    m = fmaxf(m, part[(g * 4 + 3) * CH + t]);
    p[t] = fmaxf(m, 0.f);  // relu(max) == max(relu)
  }
  __syncthreads();
  if (t < LH) {
    float a = bl1[t];
#pragma unroll 4
    for (int k = 0; k < CH; ++k) a += p[k] * Wl1[k * LH + t];
    hs[t] = fmaxf(a, 0.f);
  }
  __syncthreads();
  if (t < NC) {
    float a = bl2[t];
#pragma unroll 4
    for (int k = 0; k < LH; ++k) a += hs[k] * Wl2[k * NC + t];
    out[g * NC + t] = a;
  }
}

}  // namespace

extern "C" void kernel_launch(void* const* d_in, const int* in_sizes, int n_in,
                              void* d_out, int out_size, void* d_ws, size_t ws_size,
                              hipStream_t stream) {
  const float* x   = (const float*)d_in[0];
  const int*   ei  = (const int*)d_in[1];
  const float* ew  = (const float*)d_in[2];
  const int*   bat = (const int*)d_in[3];
  const float* W1  = (const float*)d_in[4];
  const float* b1  = (const float*)d_in[5];
  const float* W2  = (const float*)d_in[6];
  const float* b2  = (const float*)d_in[7];
  const float* W3  = (const float*)d_in[8];
  const float* b3  = (const float*)d_in[9];
  const float* Wl1 = (const float*)d_in[10];
  const float* bl1 = (const float*)d_in[11];
  const float* Wl2 = (const float*)d_in[12];
  const float* bl2 = (const float*)d_in[13];
  float* out = (float*)d_out;

  // workspace carve-up (256B aligned)
  char* base = (char*)d_ws;
  size_t o = 0;
  auto carve = [&](size_t bytes) {
    char* p = base + o;
    o = (o + bytes + 255) & ~(size_t)255;
    return p;
  };
  float* dinv   = (float*)carve(NN * 4);       // deg -> dinv in place
  int*   cnt    = (int*)carve(NN * 4);
  int*   offs   = (int*)carve(NN * 4);
  int*   cursor = (int*)carve(NN * 4);
  int*   bsum   = (int*)carve(256 * 4);
  int*   gstart = (int*)carve((NG + 1) * 4);
  float* part   = (float*)carve(NG * 4 * CH * 4);
  int2*  epack  = (int2*)carve((size_t)NE * 8);
  float* Y      = (float*)carve((size_t)NN * CH * 4);
  float* H      = (float*)carve((size_t)NN * CH * 4);
  (void)ws_size; (void)n_in; (void)in_sizes; (void)out_size;

  const int GB_N = NB_NODES;                 // 196
  const int GB_E = (NE + 255) / 256;         // 3125
  const int GB_G = (NN + 63) / 64;           // 782 gemm blocks
  const int GB_A = (NN + 7) / 8;             // agg blocks

  // graph structure (shared by all 3 conv layers)
  k_init<<<GB_N, 256, 0, stream>>>(dinv, cnt);
  k_count<<<GB_E, 256, 0, stream>>>(ei, ew, dinv, cnt);
  k_dinv<<<GB_N, 256, 0, stream>>>(dinv);
  k_scan1<<<GB_N, 256, 0, stream>>>(cnt, offs, bsum);
  k_scan2<<<1, 256, 0, stream>>>(bsum);
  k_scan3<<<GB_N, 256, 0, stream>>>(cnt, offs, bsum, cursor);
  k_fill<<<GB_E, 256, 0, stream>>>(ei, ew, dinv, cursor, epack);

  // layer 1
  k_gemm<FIN><<<GB_G, 128, 0, stream>>>(x, W1, Y);
  k_agg<true><<<GB_A, 256, 0, stream>>>(Y, offs, cnt, epack, dinv, b1, H);
  // layer 2
  k_gemm<CH><<<GB_G, 128, 0, stream>>>(H, W2, Y);
  k_agg<true><<<GB_A, 256, 0, stream>>>(Y, offs, cnt, epack, dinv, b2, H);
  // layer 3
  k_gemm<CH><<<GB_G, 128, 0, stream>>>(H, W3, Y);
  k_agg<false><<<GB_A, 256, 0, stream>>>(Y, offs, cnt, epack, dinv, b3, H);

  // pool + MLP
  k_gstart<<<GB_N, 256, 0, stream>>>(bat, gstart);
  k_pool<<<dim3(NG, 4), 128, 0, stream>>>(H, gstart, part);
  k_mlp<<<NG, 128, 0, stream>>>(part, Wl1, bl1, Wl2, bl2, out);
}

// Round 4
// 371.255 us; speedup vs baseline: 1.3824x; 1.1525x over previous
//
#include <hip/hip_runtime.h>
#include <math.h>

namespace {

constexpr int NN  = 50000;   // nodes
constexpr int NE  = 800000;  // edges
constexpr int FIN = 128;     // in features
constexpr int CH  = 96;      // conv hidden
constexpr int LH  = 64;      // lin hidden
constexpr int NC  = 10;      // classes
constexpr int NG  = 128;     // graphs
constexpr int NB_NODES = (NN + 255) / 256;  // 196 blocks over nodes

// ---------------- graph-structure build (once per call) ----------------

__global__ void k_init(int* __restrict__ cnt) {
  int i = blockIdx.x * 256 + threadIdx.x;
  if (i < NN) cnt[i] = 0;
}

// one int atomic per edge; remember the slot so k_fill needs no atomic
__global__ void k_count(const int* __restrict__ ei, int* __restrict__ cnt,
                        unsigned short* __restrict__ my_slot) {
  int e = blockIdx.x * 256 + threadIdx.x;
  if (e < NE) {
    int c = ei[NE + e];  // col (destination)
    my_slot[e] = (unsigned short)atomicAdd(&cnt[c], 1);
  }
}

__global__ void k_scan1(const int* __restrict__ cnt, int* __restrict__ incl,
                        int* __restrict__ bsum) {
  __shared__ int s[256];
  int t = threadIdx.x, i = blockIdx.x * 256 + t;
  s[t] = (i < NN) ? cnt[i] : 0;
  for (int off = 1; off < 256; off <<= 1) {
    __syncthreads();
    int u = (t >= off) ? s[t - off] : 0;
    __syncthreads();
    s[t] += u;
  }
  if (i < NN) incl[i] = s[t];
  if (t == 255) bsum[blockIdx.x] = s[255];
}

__global__ void k_scan2(int* __restrict__ bsum) {
  __shared__ int s[256];
  int t = threadIdx.x;
  int v = (t < NB_NODES) ? bsum[t] : 0;
  s[t] = v;
  for (int off = 1; off < 256; off <<= 1) {
    __syncthreads();
    int u = (t >= off) ? s[t - off] : 0;
    __syncthreads();
    s[t] += u;
  }
  if (t < NB_NODES) bsum[t] = s[t] - v;  // exclusive block offsets
}

__global__ void k_scan3(const int* __restrict__ cnt, int* __restrict__ offs,
                        const int* __restrict__ bsum) {
  int t = threadIdx.x, i = blockIdx.x * 256 + t;
  if (i < NN) offs[i] = offs[i] - cnt[i] + bsum[blockIdx.x];  // incl -> excl + base
}

// atomic-free CSR fill: store (src, raw edge weight)
__global__ void k_fill(const int* __restrict__ ei, const float* __restrict__ ew,
                       const int* __restrict__ offs,
                       const unsigned short* __restrict__ my_slot,
                       int2* __restrict__ epack) {
  int e = blockIdx.x * 256 + threadIdx.x;
  if (e < NE) {
    int r = ei[e], c = ei[NE + e];
    epack[offs[c] + (int)my_slot[e]] = make_int2(r, __float_as_int(ew[e]));
  }
}

// dinv[n] = rsqrt(1 + sum of in-edge weights) from CSR (no atomics)
__global__ void k_deg(const int* __restrict__ offs, const int* __restrict__ cnt,
                      const int2* __restrict__ epack, float* __restrict__ dinv) {
  int n = blockIdx.x * 256 + threadIdx.x;
  if (n < NN) {
    int s = offs[n], e = s + cnt[n];
    float d = 1.0f;  // self-loop weight
    for (int j = s; j < e; ++j) d += __int_as_float(epack[j].y);
    dinv[n] = 1.0f / sqrtf(d);  // d >= 1 always
  }
}

// rewrite epack.y with final coefficient dinv[src]*ew*dinv[dst]
__global__ void k_scale(const int* __restrict__ offs, const int* __restrict__ cnt,
                        const float* __restrict__ dinv, int2* __restrict__ epack) {
  int n = blockIdx.x * 256 + threadIdx.x;
  if (n < NN) {
    int s = offs[n], e = s + cnt[n];
    float dn = dinv[n];
    for (int j = s; j < e; ++j) {
      int2 p = epack[j];
      epack[j].y = __float_as_int(dinv[p.x] * __int_as_float(p.y) * dn);
    }
  }
}

// ---------------- GEMM: Y[NN][CH] = X[NN][K] @ W[K][CH] ----------------
// 64-node tile, 128 threads; thread = (a = tid>>3 in [0,16), cg = tid&7).
// Register micro-tile: 4 nodes (a, a+16, a+32, a+48) x 12 cols (cg*12..).
// K chunked at KC=32: sW[32][96] + sX[64][33] -> 20.7KB LDS.

template <int K>
__global__ __launch_bounds__(128) void k_gemm(const float* __restrict__ X,
                                              const float* __restrict__ Wg,
                                              float* __restrict__ Y) {
  constexpr int KC  = 32;
  constexpr int LDX = KC + 1;  // stride-33 rows -> conflict-free x reads
  __shared__ float sX[64 * LDX];
  __shared__ float sW[KC * CH];
  int tid = threadIdx.x;
  int n0 = blockIdx.x * 64;
  int a = tid >> 3, cg = tid & 7;
  float acc[4][12];
#pragma unroll
  for (int j = 0; j < 4; ++j)
#pragma unroll
    for (int i = 0; i < 12; ++i) acc[j][i] = 0.f;

  for (int kc = 0; kc < K; kc += KC) {
    __syncthreads();  // protect previous chunk's LDS reads
    {
      const float4* src = (const float4*)(Wg + (size_t)kc * CH);
      float4* dst = (float4*)sW;
#pragma unroll
      for (int i = 0; i < 6; ++i) dst[tid + i * 128] = src[tid + i * 128];
    }
    {
#pragma unroll
      for (int p = 0; p < 4; ++p) {
        int i = tid + p * 128;
        int r = i >> 3, c = i & 7;
        int n = n0 + r;
        float4 v = (n < NN) ? *(const float4*)(X + (size_t)n * K + kc + c * 4)
                            : make_float4(0.f, 0.f, 0.f, 0.f);
        float* d = &sX[r * LDX + c * 4];
        d[0] = v.x; d[1] = v.y; d[2] = v.z; d[3] = v.w;
      }
    }
    __syncthreads();
#pragma unroll 8
    for (int k = 0; k < KC; ++k) {
      float xv[4];
#pragma unroll
      for (int j = 0; j < 4; ++j) xv[j] = sX[(a + j * 16) * LDX + k];
      const float4* wr = (const float4*)&sW[k * CH + cg * 12];
      float4 w0 = wr[0], w1 = wr[1], w2 = wr[2];
#pragma unroll
      for (int j = 0; j < 4; ++j) {
        acc[j][0] += xv[j] * w0.x; acc[j][1]  += xv[j] * w0.y;
        acc[j][2] += xv[j] * w0.z; acc[j][3]  += xv[j] * w0.w;
        acc[j][4] += xv[j] * w1.x; acc[j][5]  += xv[j] * w1.y;
        acc[j][6] += xv[j] * w1.z; acc[j][7]  += xv[j] * w1.w;
        acc[j][8] += xv[j] * w2.x; acc[j][9]  += xv[j] * w2.y;
        acc[j][10] += xv[j] * w2.z; acc[j][11] += xv[j] * w2.w;
      }
    }
  }
#pragma unroll
  for (int j = 0; j < 4; ++j) {
    int n = n0 + a + j * 16;
    if (n < NN) {
      float4* o = (float4*)&Y[(size_t)n * CH + cg * 12];
      o[0] = make_float4(acc[j][0], acc[j][1], acc[j][2], acc[j][3]);
      o[1] = make_float4(acc[j][4], acc[j][5], acc[j][6], acc[j][7]);
      o[2] = make_float4(acc[j][8], acc[j][9], acc[j][10], acc[j][11]);
    }
  }
}

// ---------------- aggregation: H[n] = dinv[n]^2*Y[n] + sum_e coef*Y[src] + b --------
// 8 nodes/block, 32 lanes/node (24 active), float4 feature chunks.

template <bool RELU>
__global__ __launch_bounds__(256) void k_agg(const float* __restrict__ Y,
                                             const int* __restrict__ offs,
                                             const int* __restrict__ cnt,
                                             const int2* __restrict__ epack,
                                             const float* __restrict__ dinv,
                                             const float* __restrict__ bias,
                                             float* __restrict__ H) {
  int tid = threadIdx.x;
  int nl = tid >> 5;
  int fq = tid & 31;
  int n = blockIdx.x * 8 + nl;
  if (n >= NN || fq >= CH / 4) return;
  const float4* Y4 = (const float4*)Y;
  float d = dinv[n];
  float sc = d * d;
  float4 sv = Y4[n * (CH / 4) + fq];
  float ax = sc * sv.x, ay = sc * sv.y, az = sc * sv.z, aw = sc * sv.w;
  int s = offs[n], e = s + cnt[n];
  for (int j = s; j < e; ++j) {
    int2 ep = epack[j];
    float cf = __int_as_float(ep.y);
    float4 yv = Y4[ep.x * (CH / 4) + fq];
    ax += cf * yv.x; ay += cf * yv.y; az += cf * yv.z; aw += cf * yv.w;
  }
  float4 bv = ((const float4*)bias)[fq];
  ax += bv.x; ay += bv.y; az += bv.z; aw += bv.w;
  if (RELU) {
    ax = fmaxf(ax, 0.f); ay = fmaxf(ay, 0.f);
    az = fmaxf(az, 0.f); aw = fmaxf(aw, 0.f);
  }
  ((float4*)H)[n * (CH / 4) + fq] = make_float4(ax, ay, az, aw);
}

// ---------------- pool + MLP ----------------

__global__ void k_gstart(const int* __restrict__ batch, int* __restrict__ gstart) {
  int i = blockIdx.x * 256 + threadIdx.x;
  if (i < NN) {
    int g = batch[i];
    if (i == 0 || batch[i - 1] != g) gstart[g] = i;
    if (i == NN - 1) gstart[NG] = NN;
  }
}

__global__ void k_pool(const float* __restrict__ H, const int* __restrict__ gstart,
                       float* __restrict__ part) {
  int g = blockIdx.x, q = blockIdx.y, f = threadIdx.x;
  if (f >= CH) return;
  int s = gstart[g], e = gstart[g + 1];
  int len = e - s;
  int a = s + (int)(((long long)len * q) / 4);
  int b = s + (int)(((long long)len * (q + 1)) / 4);
  float m = -INFINITY;
  for (int n = a; n < b; ++n) m = fmaxf(m, H[n * CH + f]);
  part[(g * 4 + q) * CH + f] = m;
}

__global__ void k_mlp(const float* __restrict__ part, const float* __restrict__ Wl1,
                      const float* __restrict__ bl1, const float* __restrict__ Wl2,
                      const float* __restrict__ bl2, float* __restrict__ out) {
  __shared__ float p[CH];
  __shared__ float hs[LH];
  int g = blockIdx.x, t = threadIdx.x;
  if (t < CH) {
    float m = part[(g * 4 + 0) * CH + t];
    m = fmaxf(m, part[(g * 4 + 1) * CH + t]);
    m = fmaxf(m, part[(g * 4 + 2) * CH + t]);
    m = fmaxf(m, part[(g * 4 + 3) * CH + t]);
    p[t] = fmaxf(m, 0.f);  // relu(max) == max(relu)
  }
  __syncthreads();
  if (t < LH) {
    float a = bl1[t];
#pragma unroll 4
    for (int k = 0; k < CH; ++k) a += p[k] * Wl1[k * LH + t];
    hs[t] = fmaxf(a, 0.f);
  }
  __syncthreads();
  if (t < NC) {
    float a = bl2[t];
#pragma unroll 4
    for (int k = 0; k < LH; ++k) a += hs[k] * Wl2[k * NC + t];
    out[g * NC + t] = a;
  }
}

}  // namespace

extern "C" void kernel_launch(void* const* d_in, const int* in_sizes, int n_in,
                              void* d_out, int out_size, void* d_ws, size_t ws_size,
                              hipStream_t stream) {
  const float* x   = (const float*)d_in[0];
  const int*   ei  = (const int*)d_in[1];
  const float* ew  = (const float*)d_in[2];
  const int*   bat = (const int*)d_in[3];
  const float* W1  = (const float*)d_in[4];
  const float* b1  = (const float*)d_in[5];
  const float* W2  = (const float*)d_in[6];
  const float* b2  = (const float*)d_in[7];
  const float* W3  = (const float*)d_in[8];
  const float* b3  = (const float*)d_in[9];
  const float* Wl1 = (const float*)d_in[10];
  const float* bl1 = (const float*)d_in[11];
  const float* Wl2 = (const float*)d_in[12];
  const float* bl2 = (const float*)d_in[13];
  float* out = (float*)d_out;

  // workspace carve-up (256B aligned)
  char* base = (char*)d_ws;
  size_t o = 0;
  auto carve = [&](size_t bytes) {
    char* p = base + o;
    o = (o + bytes + 255) & ~(size_t)255;
    return p;
  };
  float* dinv    = (float*)carve(NN * 4);
  int*   cnt     = (int*)carve(NN * 4);
  int*   offs    = (int*)carve(NN * 4);
  unsigned short* my_slot = (unsigned short*)carve((size_t)NE * 2);
  int*   bsum    = (int*)carve(256 * 4);
  int*   gstart  = (int*)carve((NG + 1) * 4);
  float* part    = (float*)carve(NG * 4 * CH * 4);
  int2*  epack   = (int2*)carve((size_t)NE * 8);
  float* Y       = (float*)carve((size_t)NN * CH * 4);
  float* H       = (float*)carve((size_t)NN * CH * 4);
  (void)ws_size; (void)n_in; (void)in_sizes; (void)out_size;

  const int GB_N = NB_NODES;                 // 196
  const int GB_E = (NE + 255) / 256;         // 3125
  const int GB_G = (NN + 63) / 64;           // 782 gemm blocks
  const int GB_A = (NN + 7) / 8;             // agg blocks

  // graph structure (shared by all 3 conv layers)
  k_init<<<GB_N, 256, 0, stream>>>(cnt);
  k_count<<<GB_E, 256, 0, stream>>>(ei, cnt, my_slot);
  k_scan1<<<GB_N, 256, 0, stream>>>(cnt, offs, bsum);
  k_scan2<<<1, 256, 0, stream>>>(bsum);
  k_scan3<<<GB_N, 256, 0, stream>>>(cnt, offs, bsum);
  k_fill<<<GB_E, 256, 0, stream>>>(ei, ew, offs, my_slot, epack);
  k_deg<<<GB_N, 256, 0, stream>>>(offs, cnt, epack, dinv);
  k_scale<<<GB_N, 256, 0, stream>>>(offs, cnt, dinv, epack);

  // layer 1
  k_gemm<FIN><<<GB_G, 128, 0, stream>>>(x, W1, Y);
  k_agg<true><<<GB_A, 256, 0, stream>>>(Y, offs, cnt, epack, dinv, b1, H);
  // layer 2
  k_gemm<CH><<<GB_G, 128, 0, stream>>>(H, W2, Y);
  k_agg<true><<<GB_A, 256, 0, stream>>>(Y, offs, cnt, epack, dinv, b2, H);
  // layer 3
  k_gemm<CH><<<GB_G, 128, 0, stream>>>(H, W3, Y);
  k_agg<false><<<GB_A, 256, 0, stream>>>(Y, offs, cnt, epack, dinv, b3, H);

  // pool + MLP
  k_gstart<<<GB_N, 256, 0, stream>>>(bat, gstart);
  k_pool<<<dim3(NG, 4), 128, 0, stream>>>(H, gstart, part);
  k_mlp<<<NG, 128, 0, stream>>>(part, Wl1, bl1, Wl2, bl2, out);
}

// Round 5
// 331.338 us; speedup vs baseline: 1.5489x; 1.1205x over previous
//
#include <hip/hip_runtime.h>
#include <math.h>

namespace {

constexpr int NN  = 50000;   // nodes
constexpr int NE  = 800000;  // edges
constexpr int FIN = 128;     // in features
constexpr int CH  = 96;      // conv hidden
constexpr int LH  = 64;      // lin hidden
constexpr int NC  = 10;      // classes
constexpr int NG  = 128;     // graphs
constexpr int NB_NODES = (NN + 255) / 256;  // 196 blocks over nodes

// ---------------- graph-structure build (once per call) ----------------

__global__ void k_init(int* __restrict__ cnt) {
  int i = blockIdx.x * 256 + threadIdx.x;
  if (i < NN) cnt[i] = 0;
}

// one int atomic per edge; remember the slot so k_fill needs no atomic
__global__ void k_count(const int* __restrict__ ei, int* __restrict__ cnt,
                        unsigned short* __restrict__ my_slot) {
  int e = blockIdx.x * 256 + threadIdx.x;
  if (e < NE) {
    int c = ei[NE + e];  // col (destination)
    my_slot[e] = (unsigned short)atomicAdd(&cnt[c], 1);
  }
}

__global__ void k_scan1(const int* __restrict__ cnt, int* __restrict__ incl,
                        int* __restrict__ bsum) {
  __shared__ int s[256];
  int t = threadIdx.x, i = blockIdx.x * 256 + t;
  s[t] = (i < NN) ? cnt[i] : 0;
  for (int off = 1; off < 256; off <<= 1) {
    __syncthreads();
    int u = (t >= off) ? s[t - off] : 0;
    __syncthreads();
    s[t] += u;
  }
  if (i < NN) incl[i] = s[t];
  if (t == 255) bsum[blockIdx.x] = s[255];
}

__global__ void k_scan2(int* __restrict__ bsum) {
  __shared__ int s[256];
  int t = threadIdx.x;
  int v = (t < NB_NODES) ? bsum[t] : 0;
  s[t] = v;
  for (int off = 1; off < 256; off <<= 1) {
    __syncthreads();
    int u = (t >= off) ? s[t - off] : 0;
    __syncthreads();
    s[t] += u;
  }
  if (t < NB_NODES) bsum[t] = s[t] - v;  // exclusive block offsets
}

__global__ void k_scan3(const int* __restrict__ cnt, int* __restrict__ offs,
                        const int* __restrict__ bsum) {
  int t = threadIdx.x, i = blockIdx.x * 256 + t;
  if (i < NN) offs[i] = offs[i] - cnt[i] + bsum[blockIdx.x];  // incl -> excl + base
}

// atomic-free CSR fill: store (src, raw edge weight)
__global__ void k_fill(const int* __restrict__ ei, const float* __restrict__ ew,
                       const int* __restrict__ offs,
                       const unsigned short* __restrict__ my_slot,
                       int2* __restrict__ epack) {
  int e = blockIdx.x * 256 + threadIdx.x;
  if (e < NE) {
    int r = ei[e], c = ei[NE + e];
    epack[offs[c] + (int)my_slot[e]] = make_int2(r, __float_as_int(ew[e]));
  }
}

// dinv[n] = rsqrt(1 + sum of in-edge weights) from CSR (no atomics)
__global__ void k_deg(const int* __restrict__ offs, const int* __restrict__ cnt,
                      const int2* __restrict__ epack, float* __restrict__ dinv) {
  int n = blockIdx.x * 256 + threadIdx.x;
  if (n < NN) {
    int s = offs[n], e = s + cnt[n];
    float d = 1.0f;  // self-loop weight
    for (int j = s; j < e; ++j) d += __int_as_float(epack[j].y);
    dinv[n] = 1.0f / sqrtf(d);  // d >= 1 always
  }
}

// rewrite epack.y with final coefficient dinv[src]*ew*dinv[dst]
__global__ void k_scale(const int* __restrict__ offs, const int* __restrict__ cnt,
                        const float* __restrict__ dinv, int2* __restrict__ epack) {
  int n = blockIdx.x * 256 + threadIdx.x;
  if (n < NN) {
    int s = offs[n], e = s + cnt[n];
    float dn = dinv[n];
    for (int j = s; j < e; ++j) {
      int2 p = epack[j];
      epack[j].y = __float_as_int(dinv[p.x] * __int_as_float(p.y) * dn);
    }
  }
}

// ---------------- GEMM: Y[NN][CH] = X[NN][K] @ W[K][CH] ----------------
// 64-node tile, 128 threads; thread = (a = tid>>3 in [0,16), cg = tid&7).
// Register micro-tile: 4 nodes (a, a+16, a+32, a+48) x 12 cols (cg*12..).
// K chunked at KC=32: sW[32][96] + sX[64][33] -> 20.7KB LDS.

template <int K>
__global__ __launch_bounds__(128) void k_gemm(const float* __restrict__ X,
                                              const float* __restrict__ Wg,
                                              float* __restrict__ Y) {
  constexpr int KC  = 32;
  constexpr int LDX = KC + 1;  // stride-33 rows -> conflict-free x reads
  __shared__ float sX[64 * LDX];
  __shared__ float sW[KC * CH];
  int tid = threadIdx.x;
  int n0 = blockIdx.x * 64;
  int a = tid >> 3, cg = tid & 7;
  float acc[4][12];
#pragma unroll
  for (int j = 0; j < 4; ++j)
#pragma unroll
    for (int i = 0; i < 12; ++i) acc[j][i] = 0.f;

  for (int kc = 0; kc < K; kc += KC) {
    __syncthreads();  // protect previous chunk's LDS reads
    {
      const float4* src = (const float4*)(Wg + (size_t)kc * CH);
      float4* dst = (float4*)sW;
#pragma unroll
      for (int i = 0; i < 6; ++i) dst[tid + i * 128] = src[tid + i * 128];
    }
    {
#pragma unroll
      for (int p = 0; p < 4; ++p) {
        int i = tid + p * 128;
        int r = i >> 3, c = i & 7;
        int n = n0 + r;
        float4 v = (n < NN) ? *(const float4*)(X + (size_t)n * K + kc + c * 4)
                            : make_float4(0.f, 0.f, 0.f, 0.f);
        float* d = &sX[r * LDX + c * 4];
        d[0] = v.x; d[1] = v.y; d[2] = v.z; d[3] = v.w;
      }
    }
    __syncthreads();
#pragma unroll 8
    for (int k = 0; k < KC; ++k) {
      float xv[4];
#pragma unroll
      for (int j = 0; j < 4; ++j) xv[j] = sX[(a + j * 16) * LDX + k];
      const float4* wr = (const float4*)&sW[k * CH + cg * 12];
      float4 w0 = wr[0], w1 = wr[1], w2 = wr[2];
#pragma unroll
      for (int j = 0; j < 4; ++j) {
        acc[j][0] += xv[j] * w0.x; acc[j][1]  += xv[j] * w0.y;
        acc[j][2] += xv[j] * w0.z; acc[j][3]  += xv[j] * w0.w;
        acc[j][4] += xv[j] * w1.x; acc[j][5]  += xv[j] * w1.y;
        acc[j][6] += xv[j] * w1.z; acc[j][7]  += xv[j] * w1.w;
        acc[j][8] += xv[j] * w2.x; acc[j][9]  += xv[j] * w2.y;
        acc[j][10] += xv[j] * w2.z; acc[j][11] += xv[j] * w2.w;
      }
    }
  }
#pragma unroll
  for (int j = 0; j < 4; ++j) {
    int n = n0 + a + j * 16;
    if (n < NN) {
      float4* o = (float4*)&Y[(size_t)n * CH + cg * 12];
      o[0] = make_float4(acc[j][0], acc[j][1], acc[j][2], acc[j][3]);
      o[1] = make_float4(acc[j][4], acc[j][5], acc[j][6], acc[j][7]);
      o[2] = make_float4(acc[j][8], acc[j][9], acc[j][10], acc[j][11]);
    }
  }
}

// ---------------- aggregation: H[n] = dinv[n]^2*Y[n] + sum_e coef*Y[src] + b --------
// 8 nodes/block, 24 lanes/node (192 threads, zero idle lanes), float4 chunks.
// Edge loop unrolled 4x: 4 independent gathers in flight per lane-group.

template <bool RELU>
__global__ __launch_bounds__(192) void k_agg(const float* __restrict__ Y,
                                             const int* __restrict__ offs,
                                             const int* __restrict__ cnt,
                                             const int2* __restrict__ epack,
                                             const float* __restrict__ dinv,
                                             const float* __restrict__ bias,
                                             float* __restrict__ H) {
  int tid = threadIdx.x;
  int nl = tid / 24;   // node slot 0..7
  int fq = tid % 24;   // float4 chunk 0..23
  int n = blockIdx.x * 8 + nl;
  if (n >= NN) return;
  const float4* Y4 = (const float4*)Y;
  float d = dinv[n];
  float sc = d * d;
  float4 sv = Y4[(size_t)n * 24 + fq];
  float ax = sc * sv.x, ay = sc * sv.y, az = sc * sv.z, aw = sc * sv.w;
  int s = offs[n], e = s + cnt[n];
  int j = s;
  int nfull = (e - s) & ~3;
  for (; j < s + nfull; j += 4) {
    int2 p0 = epack[j], p1 = epack[j + 1], p2 = epack[j + 2], p3 = epack[j + 3];
    float4 y0 = Y4[(size_t)p0.x * 24 + fq];
    float4 y1 = Y4[(size_t)p1.x * 24 + fq];
    float4 y2 = Y4[(size_t)p2.x * 24 + fq];
    float4 y3 = Y4[(size_t)p3.x * 24 + fq];
    float c0 = __int_as_float(p0.y), c1 = __int_as_float(p1.y);
    float c2 = __int_as_float(p2.y), c3 = __int_as_float(p3.y);
    ax += c0 * y0.x; ay += c0 * y0.y; az += c0 * y0.z; aw += c0 * y0.w;
    ax += c1 * y1.x; ay += c1 * y1.y; az += c1 * y1.z; aw += c1 * y1.w;
    ax += c2 * y2.x; ay += c2 * y2.y; az += c2 * y2.z; aw += c2 * y2.w;
    ax += c3 * y3.x; ay += c3 * y3.y; az += c3 * y3.z; aw += c3 * y3.w;
  }
  for (; j < e; ++j) {
    int2 ep = epack[j];
    float cf = __int_as_float(ep.y);
    float4 yv = Y4[(size_t)ep.x * 24 + fq];
    ax += cf * yv.x; ay += cf * yv.y; az += cf * yv.z; aw += cf * yv.w;
  }
  float4 bv = ((const float4*)bias)[fq];
  ax += bv.x; ay += bv.y; az += bv.z; aw += bv.w;
  if (RELU) {
    ax = fmaxf(ax, 0.f); ay = fmaxf(ay, 0.f);
    az = fmaxf(az, 0.f); aw = fmaxf(aw, 0.f);
  }
  ((float4*)H)[(size_t)n * 24 + fq] = make_float4(ax, ay, az, aw);
}

// ---------------- pool + MLP ----------------

__global__ void k_gstart(const int* __restrict__ batch, int* __restrict__ gstart) {
  int i = blockIdx.x * 256 + threadIdx.x;
  if (i < NN) {
    int g = batch[i];
    if (i == 0 || batch[i - 1] != g) gstart[g] = i;
    if (i == NN - 1) gstart[NG] = NN;
  }
}

__global__ void k_pool(const float* __restrict__ H, const int* __restrict__ gstart,
                       float* __restrict__ part) {
  int g = blockIdx.x, q = blockIdx.y, f = threadIdx.x;
  if (f >= CH) return;
  int s = gstart[g], e = gstart[g + 1];
  int len = e - s;
  int a = s + (int)(((long long)len * q) / 4);
  int b = s + (int)(((long long)len * (q + 1)) / 4);
  float m = -INFINITY;
  for (int n = a; n < b; ++n) m = fmaxf(m, H[n * CH + f]);
  part[(g * 4 + q) * CH + f] = m;
}

__global__ void k_mlp(const float* __restrict__ part, const float* __restrict__ Wl1,
                      const float* __restrict__ bl1, const float* __restrict__ Wl2,
                      const float* __restrict__ bl2, float* __restrict__ out) {
  __shared__ float p[CH];
  __shared__ float hs[LH];
  int g = blockIdx.x, t = threadIdx.x;
  if (t < CH) {
    float m = part[(g * 4 + 0) * CH + t];
    m = fmaxf(m, part[(g * 4 + 1) * CH + t]);
    m = fmaxf(m, part[(g * 4 + 2) * CH + t]);
    m = fmaxf(m, part[(g * 4 + 3) * CH + t]);
    p[t] = fmaxf(m, 0.f);  // relu(max) == max(relu)
  }
  __syncthreads();
  if (t < LH) {
    float a = bl1[t];
#pragma unroll 4
    for (int k = 0; k < CH; ++k) a += p[k] * Wl1[k * LH + t];
    hs[t] = fmaxf(a, 0.f);
  }
  __syncthreads();
  if (t < NC) {
    float a = bl2[t];
#pragma unroll 4
    for (int k = 0; k < LH; ++k) a += hs[k] * Wl2[k * NC + t];
    out[g * NC + t] = a;
  }
}

}  // namespace

extern "C" void kernel_launch(void* const* d_in, const int* in_sizes, int n_in,
                              void* d_out, int out_size, void* d_ws, size_t ws_size,
                              hipStream_t stream) {
  const float* x   = (const float*)d_in[0];
  const int*   ei  = (const int*)d_in[1];
  const float* ew  = (const float*)d_in[2];
  const int*   bat = (const int*)d_in[3];
  const float* W1  = (const float*)d_in[4];
  const float* b1  = (const float*)d_in[5];
  const float* W2  = (const float*)d_in[6];
  const float* b2  = (const float*)d_in[7];
  const float* W3  = (const float*)d_in[8];
  const float* b3  = (const float*)d_in[9];
  const float* Wl1 = (const float*)d_in[10];
  const float* bl1 = (const float*)d_in[11];
  const float* Wl2 = (const float*)d_in[12];
  const float* bl2 = (const float*)d_in[13];
  float* out = (float*)d_out;

  // workspace carve-up (256B aligned)
  char* base = (char*)d_ws;
  size_t o = 0;
  auto carve = [&](size_t bytes) {
    char* p = base + o;
    o = (o + bytes + 255) & ~(size_t)255;
    return p;
  };
  float* dinv    = (float*)carve(NN * 4);
  int*   cnt     = (int*)carve(NN * 4);
  int*   offs    = (int*)carve(NN * 4);
  unsigned short* my_slot = (unsigned short*)carve((size_t)NE * 2);
  int*   bsum    = (int*)carve(256 * 4);
  int*   gstart  = (int*)carve((NG + 1) * 4);
  float* part    = (float*)carve(NG * 4 * CH * 4);
  int2*  epack   = (int2*)carve((size_t)NE * 8);
  float* Y       = (float*)carve((size_t)NN * CH * 4);
  float* H       = (float*)carve((size_t)NN * CH * 4);
  (void)ws_size; (void)n_in; (void)in_sizes; (void)out_size;

  const int GB_N = NB_NODES;                 // 196
  const int GB_E = (NE + 255) / 256;         // 3125
  const int GB_G = (NN + 63) / 64;           // 782 gemm blocks
  const int GB_A = (NN + 7) / 8;             // agg blocks (192 thr: 8 nodes x 24 lanes)

  // graph structure (shared by all 3 conv layers)
  k_init<<<GB_N, 256, 0, stream>>>(cnt);
  k_count<<<GB_E, 256, 0, stream>>>(ei, cnt, my_slot);
  k_scan1<<<GB_N, 256, 0, stream>>>(cnt, offs, bsum);
  k_scan2<<<1, 256, 0, stream>>>(bsum);
  k_scan3<<<GB_N, 256, 0, stream>>>(cnt, offs, bsum);
  k_fill<<<GB_E, 256, 0, stream>>>(ei, ew, offs, my_slot, epack);
  k_deg<<<GB_N, 256, 0, stream>>>(offs, cnt, epack, dinv);
  k_scale<<<GB_N, 256, 0, stream>>>(offs, cnt, dinv, epack);

  // layer 1
  k_gemm<FIN><<<GB_G, 128, 0, stream>>>(x, W1, Y);
  k_agg<true><<<GB_A, 192, 0, stream>>>(Y, offs, cnt, epack, dinv, b1, H);
  // layer 2
  k_gemm<CH><<<GB_G, 128, 0, stream>>>(H, W2, Y);
  k_agg<true><<<GB_A, 192, 0, stream>>>(Y, offs, cnt, epack, dinv, b2, H);
  // layer 3
  k_gemm<CH><<<GB_G, 128, 0, stream>>>(H, W3, Y);
  k_agg<false><<<GB_A, 192, 0, stream>>>(Y, offs, cnt, epack, dinv, b3, H);

  // pool + MLP
  k_gstart<<<GB_N, 256, 0, stream>>>(bat, gstart);
  k_pool<<<dim3(NG, 4), 128, 0, stream>>>(H, gstart, part);
  k_mlp<<<NG, 128, 0, stream>>>(part, Wl1, bl1, Wl2, bl2, out);
}